// Round 2
// baseline (91.152 us; speedup 1.0000x reference)
//
#include <hip/hip_runtime.h>

#define NBINS  256
#define NCLS   20
#define CDIM   21
#define HW     (512 * 512)
#define NPIX   (8 * HW)
#define NCHUNK 256
#define CHUNK  (NPIX / NCHUNK)   // 8192, divides HW -> chunk stays in one image

__global__ __launch_bounds__(256) void zero_ws(unsigned* __restrict__ w, int n) {
    int i = blockIdx.x * 256 + threadIdx.x;
    if (i < n) w[i] = 0u;
}

// One block = one 8192-pixel chunk, ALL 20 classes.
// LDS: 20 packed histograms (low16=cnt, high16=poscnt) + labels as bytes.
__global__ __launch_bounds__(256, 5) void lovasz_hist(const float* __restrict__ pred,
                                                      const int* __restrict__ label,
                                                      unsigned* __restrict__ g_cnt,
                                                      unsigned* __restrict__ g_pos) {
    __shared__ unsigned s_hist[NCLS * NBINS];   // 20 KB
    __shared__ unsigned s_lab[CHUNK / 4];       // 8 KB, 4 labels/word
    const int tid = threadIdx.x;
    for (int i = tid; i < NCLS * NBINS; i += 256) s_hist[i] = 0u;

    const long base = (long)blockIdx.x * CHUNK;
    const int  b    = (int)(base / HW);
    const long hw0  = base - (long)b * HW;
    const int* lb   = label + base;
    for (int i = tid * 4; i < CHUNK; i += 256 * 4) {
        const int4 l = *reinterpret_cast<const int4*>(lb + i);
        s_lab[i >> 2] = (unsigned)(l.x & 255) | ((unsigned)(l.y & 255) << 8) |
                        ((unsigned)(l.z & 255) << 16) | ((unsigned)(l.w & 255) << 24);
    }
    __syncthreads();

    const float* pbase = pred + ((long)b * CDIM + 1) * HW + hw0;  // channel 1
    for (int c = 0; c < NCLS; c += 2) {
        const float* pc0 = pbase + (long)c * HW;
        const float* pc1 = pc0 + HW;
#pragma unroll
        for (int it = 0; it < CHUNK / 1024; ++it) {   // 8 iterations
            const int i = tid * 4 + it * 1024;
            float v[8];
            *reinterpret_cast<float4*>(v)     = *reinterpret_cast<const float4*>(pc0 + i);
            *reinterpret_cast<float4*>(v + 4) = *reinterpret_cast<const float4*>(pc1 + i);
            const unsigned lw = s_lab[i >> 2];        // lanes -> consecutive words
#pragma unroll
            for (int j = 0; j < 4; ++j) {
                const int lv = (lw >> (8 * j)) & 255;
#pragma unroll
                for (int k = 0; k < 2; ++k) {
                    float p = 1.0f / (1.0f + __expf(-v[k * 4 + j]));
                    p = fminf(fmaxf(p, 1e-4f), 1.0f - 1e-4f);
                    const bool  pos = (lv == c + 1 + k);
                    const float e   = pos ? 1.0f - p : p;
                    int bin = (int)(e * (float)NBINS);
                    bin = bin > NBINS - 1 ? NBINS - 1 : bin;
                    atomicAdd(&s_hist[(c + k) * NBINS + bin], pos ? 0x10001u : 1u);
                }
            }
        }
    }
    __syncthreads();

    for (int i = tid; i < NCLS * NBINS; i += 256) {
        const unsigned v = s_hist[i];
        if (v) {
            atomicAdd(&g_cnt[i], v & 0xFFFFu);
            const unsigned p = v >> 16;
            if (p) atomicAdd(&g_pos[i], p);
        }
    }
}

// Per-class descending scan over 256 bins + Lovasz-grad weighted sum. One bin/thread.
__global__ __launch_bounds__(256) void lovasz_scan(const unsigned* __restrict__ g_cnt,
                                                   const unsigned* __restrict__ g_pos,
                                                   float* __restrict__ out_pc) {
    const int cls = blockIdx.x;
    const int tid = threadIdx.x;
    const int bin = NBINS - 1 - tid;              // descending error order
    const unsigned lc = g_cnt[cls * NBINS + bin];
    const unsigned lp = g_pos[cls * NBINS + bin];

    __shared__ unsigned sc[256], sp[256];
    sc[tid] = lc;
    sp[tid] = lp;
    __syncthreads();

    unsigned exc_c = 0, exc_p = 0, G = 0;
    for (int i = 0; i < 256; ++i) {               // tiny kernel; naive scan fine
        if (i < tid) { exc_c += sc[i]; exc_p += sp[i]; }
        G += sp[i];
    }

    float contrib = 0.0f;
    if (G > 0 && lc > 0) {
        const float fG = (float)G;
        // J(i,m) = 1 - (G-m)/(G+i-m); exact in f32 (counts < 2^23)
        const float Jprev = 1.0f - (fG - (float)exc_p) / (fG + (float)(exc_c - exc_p));
        const unsigned ic = exc_c + lc, mp = exc_p + lp;
        const float Jcur  = 1.0f - (fG - (float)mp) / (fG + (float)(ic - mp));
        const float mid   = ((float)bin + 0.5f) * (1.0f / (float)NBINS);
        contrib = mid * (Jcur - Jprev);
    }

    __shared__ float sf[256];
    sf[tid] = contrib;
    __syncthreads();
    for (int s = 128; s > 0; s >>= 1) {
        if (tid < s) sf[tid] += sf[tid + s];
        __syncthreads();
    }
    if (tid == 0) {
        out_pc[cls * 2]     = sf[0];
        out_pc[cls * 2 + 1] = (G > 0) ? 1.0f : 0.0f;
    }
}

__global__ void lovasz_final(const float* __restrict__ out_pc, float* __restrict__ out) {
    if (threadIdx.x == 0 && blockIdx.x == 0) {
        float s = 0.0f, n = 0.0f;
        for (int c = 0; c < NCLS; ++c) {
            s += out_pc[c * 2];
            n += out_pc[c * 2 + 1];
        }
        out[0] = s / n;
    }
}

extern "C" void kernel_launch(void* const* d_in, const int* in_sizes, int n_in,
                              void* d_out, int out_size, void* d_ws, size_t ws_size,
                              hipStream_t stream) {
    const float* pred  = (const float*)d_in[0];
    const int*   label = (const int*)d_in[1];

    unsigned* g_cnt  = (unsigned*)d_ws;
    unsigned* g_pos  = g_cnt + (size_t)NCLS * NBINS;
    float*    out_pc = (float*)(g_pos + (size_t)NCLS * NBINS);
    float*    out    = (float*)d_out;

    const int nzero = NCLS * NBINS * 2;
    zero_ws<<<(nzero + 255) / 256, 256, 0, stream>>>(g_cnt, nzero);
    lovasz_hist<<<NCHUNK, 256, 0, stream>>>(pred, label, g_cnt, g_pos);
    lovasz_scan<<<NCLS, 256, 0, stream>>>(g_cnt, g_pos, out_pc);
    lovasz_final<<<1, 64, 0, stream>>>(out_pc, out);
}

// Round 3
// 80.657 us; speedup vs baseline: 1.1301x; 1.1301x over previous
//
#include <hip/hip_runtime.h>

#define NBINS  128
#define NCLS   20
#define CDIM   21
#define HW     (512 * 512)
#define NPIX   (8 * HW)
#define NCHUNK 2048
#define CHUNK  (NPIX / NCHUNK)   // 1024, divides HW -> chunk stays in one image

__global__ __launch_bounds__(256) void zero_ws(unsigned* __restrict__ w, int n) {
    int i = blockIdx.x * 256 + threadIdx.x;
    if (i < n) w[i] = 0u;
}

// One block = one 1024-pixel chunk, ALL 20 classes. 8 blocks/CU resident.
// LDS: 20 packed 128-bin histograms (low16=cnt, high16=pos) + labels as bytes.
__global__ __launch_bounds__(256, 8) void lovasz_hist(const float* __restrict__ pred,
                                                      const int* __restrict__ label,
                                                      unsigned long long* __restrict__ g_hist) {
    __shared__ unsigned s_hist[NCLS * NBINS];   // 10 KB
    __shared__ unsigned s_lab[CHUNK / 4];       // 1 KB, 4 labels/word
    const int tid = threadIdx.x;
    for (int i = tid; i < NCLS * NBINS; i += 256) s_hist[i] = 0u;

    const long base = (long)blockIdx.x * CHUNK;
    const int  b    = (int)(base / HW);
    const long hw0  = base - (long)b * HW;
    {
        const int4 l = *reinterpret_cast<const int4*>(label + base + tid * 4);
        s_lab[tid] = (unsigned)(l.x & 255) | ((unsigned)(l.y & 255) << 8) |
                     ((unsigned)(l.z & 255) << 16) | ((unsigned)(l.w & 255) << 24);
    }
    __syncthreads();

    const float* pbase = pred + ((long)b * CDIM + 1) * HW + hw0 + tid * 4;  // channel 1
    const unsigned lw = s_lab[tid];
#pragma unroll 1
    for (int c = 0; c < NCLS; c += 2) {
        const float4 x0 = *reinterpret_cast<const float4*>(pbase + (long)c * HW);
        const float4 x1 = *reinterpret_cast<const float4*>(pbase + (long)(c + 1) * HW);
        float v[8];
        *reinterpret_cast<float4*>(v)     = x0;
        *reinterpret_cast<float4*>(v + 4) = x1;
#pragma unroll
        for (int j = 0; j < 4; ++j) {
            const int lv = (lw >> (8 * j)) & 255;
#pragma unroll
            for (int k = 0; k < 2; ++k) {
                const float xv  = v[k * 4 + j];
                const bool  pos = (lv == c + 1 + k);
                // e = clamp(sigmoid(pos ? -x : x)): |mask - p| with p clamped
                const float s = pos ? -xv : xv;
                float e = __builtin_amdgcn_rcpf(1.0f + __expf(-s));
                e = fminf(fmaxf(e, 1e-4f), 1.0f - 1e-4f);
                int bin = (int)(e * (float)NBINS);
                bin = bin > NBINS - 1 ? NBINS - 1 : bin;
                atomicAdd(&s_hist[(c + k) * NBINS + bin], pos ? 0x10001u : 1u);
            }
        }
    }
    __syncthreads();

    for (int i = tid; i < NCLS * NBINS; i += 256) {
        const unsigned v = s_hist[i];
        if (v) {
            const unsigned long long pk =
                (unsigned long long)(v & 0xFFFFu) | ((unsigned long long)(v >> 16) << 32);
            atomicAdd(&g_hist[i], pk);
        }
    }
}

// Per-class descending scan over 128 bins + Lovasz-grad weighted sum. One bin/thread.
__global__ __launch_bounds__(128) void lovasz_scan(const unsigned long long* __restrict__ g_hist,
                                                   float* __restrict__ out_pc) {
    const int cls = blockIdx.x;
    const int tid = threadIdx.x;
    const int bin = NBINS - 1 - tid;              // descending error order
    const unsigned long long v = g_hist[cls * NBINS + bin];
    const unsigned lc = (unsigned)(v & 0xFFFFFFFFull);
    const unsigned lp = (unsigned)(v >> 32);

    __shared__ unsigned sc[NBINS], sp[NBINS];
    sc[tid] = lc;
    sp[tid] = lp;
    __syncthreads();

    unsigned exc_c = 0, exc_p = 0, G = 0;
    for (int i = 0; i < NBINS; ++i) {             // tiny kernel; naive scan fine
        if (i < tid) { exc_c += sc[i]; exc_p += sp[i]; }
        G += sp[i];
    }

    float contrib = 0.0f;
    if (G > 0 && lc > 0) {
        const float fG = (float)G;
        // J(i,m) = 1 - (G-m)/(G+i-m); exact in f32 (counts < 2^23)
        const float Jprev = 1.0f - (fG - (float)exc_p) / (fG + (float)(exc_c - exc_p));
        const unsigned ic = exc_c + lc, mp = exc_p + lp;
        const float Jcur  = 1.0f - (fG - (float)mp) / (fG + (float)(ic - mp));
        const float mid   = ((float)bin + 0.5f) * (1.0f / (float)NBINS);
        contrib = mid * (Jcur - Jprev);
    }

    __shared__ float sf[NBINS];
    sf[tid] = contrib;
    __syncthreads();
    for (int s = NBINS / 2; s > 0; s >>= 1) {
        if (tid < s) sf[tid] += sf[tid + s];
        __syncthreads();
    }
    if (tid == 0) {
        out_pc[cls * 2]     = sf[0];
        out_pc[cls * 2 + 1] = (G > 0) ? 1.0f : 0.0f;
    }
}

__global__ void lovasz_final(const float* __restrict__ out_pc, float* __restrict__ out) {
    if (threadIdx.x == 0 && blockIdx.x == 0) {
        float s = 0.0f, n = 0.0f;
        for (int c = 0; c < NCLS; ++c) {
            s += out_pc[c * 2];
            n += out_pc[c * 2 + 1];
        }
        out[0] = s / n;
    }
}

extern "C" void kernel_launch(void* const* d_in, const int* in_sizes, int n_in,
                              void* d_out, int out_size, void* d_ws, size_t ws_size,
                              hipStream_t stream) {
    const float* pred  = (const float*)d_in[0];
    const int*   label = (const int*)d_in[1];

    unsigned long long* g_hist = (unsigned long long*)d_ws;
    float* out_pc = (float*)(g_hist + (size_t)NCLS * NBINS);
    float* out    = (float*)d_out;

    const int nzero = NCLS * NBINS * 2;  // u64 hist as u32 words
    zero_ws<<<(nzero + 255) / 256, 256, 0, stream>>>((unsigned*)g_hist, nzero);
    lovasz_hist<<<NCHUNK, 256, 0, stream>>>(pred, label, g_hist);
    lovasz_scan<<<NCLS, NBINS, 0, stream>>>(g_hist, out_pc);
    lovasz_final<<<1, 64, 0, stream>>>(out_pc, out);
}

// Round 4
// 60.778 us; speedup vs baseline: 1.4997x; 1.3271x over previous
//
#include <hip/hip_runtime.h>

#define NBINS  128
#define NCLS   20
#define CDIM   21
#define HW     (512 * 512)
#define NPIX   (8 * HW)
#define NCHUNK 2048
#define CHUNK  (NPIX / NCHUNK)   // 1024 pixels/block; divides HW
#define NCOPY  32                // global histogram replicas (merge contention /32)

__global__ __launch_bounds__(256) void zero_ws(unsigned* __restrict__ w, int n) {
    int i = blockIdx.x * 256 + threadIdx.x;
    if (i < n) w[i] = 0u;
}

// One block = one 1024-pixel chunk, all 20 classes. 4 blocks/CU, 21-deep load ILP.
__global__ __launch_bounds__(256, 4) void lovasz_hist(const float* __restrict__ pred,
                                                      const int* __restrict__ label,
                                                      unsigned long long* __restrict__ g_hist) {
    __shared__ unsigned s_hist[NCLS * NBINS];   // 10 KB
    const int tid = threadIdx.x;

    const long base = (long)blockIdx.x * CHUNK;
    const int  b    = (int)(base / HW);
    const long hw0  = base - (long)b * HW;

    // Issue ALL loads first: 20 pred float4 + 1 label int4, independent.
    const float* pbase = pred + ((long)b * CDIM + 1) * HW + hw0 + tid * 4;
    float4 x[NCLS];
#pragma unroll
    for (int c = 0; c < NCLS; ++c)
        x[c] = *reinterpret_cast<const float4*>(pbase + (long)c * HW);
    const int4 l = *reinterpret_cast<const int4*>(label + base + tid * 4);

    // Zero LDS while loads are in flight.
    for (int i = tid; i < NCLS * NBINS; i += 256) s_hist[i] = 0u;
    __syncthreads();

#pragma unroll
    for (int j = 0; j < 4; ++j) {
        const int lv = (j == 0) ? l.x : (j == 1) ? l.y : (j == 2) ? l.z : l.w;
#pragma unroll
        for (int c = 0; c < NCLS; ++c) {
            const float xv  = (j == 0) ? x[c].x : (j == 1) ? x[c].y : (j == 2) ? x[c].z : x[c].w;
            const bool  pos = (lv == c + 1);
            // e = clamp(sigmoid(pos ? -x : x)) == |mask - clamp(sigmoid(x))|
            const float s = pos ? -xv : xv;
            float e = 1.0f / (1.0f + __expf(-s));
            e = fminf(fmaxf(e, 1e-4f), 1.0f - 1e-4f);
            int bin = (int)(e * (float)NBINS);
            bin = bin > NBINS - 1 ? NBINS - 1 : bin;
            atomicAdd(&s_hist[c * NBINS + bin], pos ? 0x10001u : 1u);
        }
    }
    __syncthreads();

    // Merge into one of NCOPY global replicas -> contention /NCOPY.
    unsigned long long* gh = g_hist + (size_t)(blockIdx.x & (NCOPY - 1)) * (NCLS * NBINS);
    for (int i = tid; i < NCLS * NBINS; i += 256) {
        const unsigned v = s_hist[i];
        if (v) {
            const unsigned long long pk =
                (unsigned long long)(v & 0xFFFFu) | ((unsigned long long)(v >> 16) << 32);
            atomicAdd(&gh[i], pk);
        }
    }
}

// Per-class: sum the NCOPY replicas, descending scan over 128 bins, Lovasz-grad sum.
__global__ __launch_bounds__(128) void lovasz_scan(const unsigned long long* __restrict__ g_hist,
                                                   float* __restrict__ out_pc) {
    const int cls = blockIdx.x;
    const int tid = threadIdx.x;
    const int bin = NBINS - 1 - tid;              // descending error order
    unsigned lc = 0, lp = 0;
    for (int r = 0; r < NCOPY; ++r) {
        const unsigned long long v = g_hist[(size_t)r * (NCLS * NBINS) + cls * NBINS + bin];
        lc += (unsigned)(v & 0xFFFFFFFFull);
        lp += (unsigned)(v >> 32);
    }

    __shared__ unsigned sc[NBINS], sp[NBINS];
    sc[tid] = lc;
    sp[tid] = lp;
    __syncthreads();

    unsigned exc_c = 0, exc_p = 0, G = 0;
    for (int i = 0; i < NBINS; ++i) {             // tiny kernel; naive scan fine
        if (i < tid) { exc_c += sc[i]; exc_p += sp[i]; }
        G += sp[i];
    }

    float contrib = 0.0f;
    if (G > 0 && lc > 0) {
        const float fG = (float)G;
        // J(i,m) = 1 - (G-m)/(G+i-m); exact in f32 (counts < 2^23)
        const float Jprev = 1.0f - (fG - (float)exc_p) / (fG + (float)(exc_c - exc_p));
        const unsigned ic = exc_c + lc, mp = exc_p + lp;
        const float Jcur  = 1.0f - (fG - (float)mp) / (fG + (float)(ic - mp));
        const float mid   = ((float)bin + 0.5f) * (1.0f / (float)NBINS);
        contrib = mid * (Jcur - Jprev);
    }

    __shared__ float sf[NBINS];
    sf[tid] = contrib;
    __syncthreads();
    for (int s = NBINS / 2; s > 0; s >>= 1) {
        if (tid < s) sf[tid] += sf[tid + s];
        __syncthreads();
    }
    if (tid == 0) {
        out_pc[cls * 2]     = sf[0];
        out_pc[cls * 2 + 1] = (G > 0) ? 1.0f : 0.0f;
    }
}

__global__ void lovasz_final(const float* __restrict__ out_pc, float* __restrict__ out) {
    if (threadIdx.x == 0 && blockIdx.x == 0) {
        float s = 0.0f, n = 0.0f;
        for (int c = 0; c < NCLS; ++c) {
            s += out_pc[c * 2];
            n += out_pc[c * 2 + 1];
        }
        out[0] = s / n;
    }
}

extern "C" void kernel_launch(void* const* d_in, const int* in_sizes, int n_in,
                              void* d_out, int out_size, void* d_ws, size_t ws_size,
                              hipStream_t stream) {
    const float* pred  = (const float*)d_in[0];
    const int*   label = (const int*)d_in[1];

    unsigned long long* g_hist = (unsigned long long*)d_ws;
    float* out_pc = (float*)(g_hist + (size_t)NCOPY * NCLS * NBINS);
    float* out    = (float*)d_out;

    const int nzero = NCOPY * NCLS * NBINS * 2;  // u64 hist as u32 words
    zero_ws<<<(nzero + 255) / 256, 256, 0, stream>>>((unsigned*)g_hist, nzero);
    lovasz_hist<<<NCHUNK, 256, 0, stream>>>(pred, label, g_hist);
    lovasz_scan<<<NCLS, NBINS, 0, stream>>>(g_hist, out_pc);
    lovasz_final<<<1, 64, 0, stream>>>(out_pc, out);
}

// Round 5
// 58.056 us; speedup vs baseline: 1.5701x; 1.0469x over previous
//
#include <hip/hip_runtime.h>

#define NBINS  128
#define NCLS   20
#define CDIM   21
#define HW     (512 * 512)
#define NPIX   (8 * HW)
#define NCHUNK 2048
#define CHUNK  (NPIX / NCHUNK)   // 1024 pixels/block; divides HW
#define NCOPY  32                // global histogram replicas (merge contention /32)

__global__ __launch_bounds__(256) void zero_ws(unsigned* __restrict__ w, int n) {
    int i = blockIdx.x * 256 + threadIdx.x;
    if (i < n) w[i] = 0u;
}

// One block = one 1024-pixel chunk, all 20 classes.
// All 21 loads issued before ANY compute (sched_barrier pins the issue order),
// giving ~21KB of memory-level parallelism per wave.
__global__ __launch_bounds__(256, 4) void lovasz_hist(const float* __restrict__ pred,
                                                      const int* __restrict__ label,
                                                      unsigned long long* __restrict__ g_hist) {
    __shared__ unsigned s_hist[NCLS * NBINS];   // 10 KB
    const int tid = threadIdx.x;

    const long base = (long)blockIdx.x * CHUNK;
    const int  b    = (int)(base / HW);
    const long hw0  = base - (long)b * HW;

    const float* pbase = pred + ((long)b * CDIM + 1) * HW + hw0 + tid * 4;
    float4 x[NCLS];
#pragma unroll
    for (int c = 0; c < NCLS; ++c)
        x[c] = *reinterpret_cast<const float4*>(pbase + (long)c * HW);
    const int4 l = *reinterpret_cast<const int4*>(label + base + tid * 4);

    // Nothing may be scheduled above this point from below: all 21 loads stay issued.
    __builtin_amdgcn_sched_barrier(0);

    // Zero LDS while the loads are in flight.
    for (int i = tid; i < NCLS * NBINS; i += 256) s_hist[i] = 0u;
    __syncthreads();

#pragma unroll
    for (int j = 0; j < 4; ++j) {
        const int lv = (j == 0) ? l.x : (j == 1) ? l.y : (j == 2) ? l.z : l.w;
#pragma unroll
        for (int c = 0; c < NCLS; ++c) {
            const float xv  = (j == 0) ? x[c].x : (j == 1) ? x[c].y : (j == 2) ? x[c].z : x[c].w;
            const bool  pos = (lv == c + 1);
            // e = sigmoid(pos ? -xv : xv) = 1/(1+exp(pos ? xv : -xv)); clamps fold
            // into bins 0/127 (only the top guard is needed: rcp may round to 1.0).
            const float q = __expf(pos ? xv : -xv);
            const float r = __builtin_amdgcn_rcpf(1.0f + q);
            int bin = (int)(r * 128.0f);
            bin = bin > 127 ? 127 : bin;
            atomicAdd(&s_hist[c * NBINS + bin], pos ? 0x10001u : 1u);
        }
    }
    __syncthreads();

    // Merge into one of NCOPY global replicas -> contention /NCOPY.
    unsigned long long* gh = g_hist + (size_t)(blockIdx.x & (NCOPY - 1)) * (NCLS * NBINS);
    for (int i = tid; i < NCLS * NBINS; i += 256) {
        const unsigned v = s_hist[i];
        if (v) {
            const unsigned long long pk =
                (unsigned long long)(v & 0xFFFFu) | ((unsigned long long)(v >> 16) << 32);
            atomicAdd(&gh[i], pk);
        }
    }
}

// Per-class: sum the NCOPY replicas, descending scan over 128 bins, Lovasz-grad sum.
__global__ __launch_bounds__(128) void lovasz_scan(const unsigned long long* __restrict__ g_hist,
                                                   float* __restrict__ out_pc) {
    const int cls = blockIdx.x;
    const int tid = threadIdx.x;
    const int bin = NBINS - 1 - tid;              // descending error order
    unsigned lc = 0, lp = 0;
    for (int r = 0; r < NCOPY; ++r) {
        const unsigned long long v = g_hist[(size_t)r * (NCLS * NBINS) + cls * NBINS + bin];
        lc += (unsigned)(v & 0xFFFFFFFFull);
        lp += (unsigned)(v >> 32);
    }

    __shared__ unsigned sc[NBINS], sp[NBINS];
    sc[tid] = lc;
    sp[tid] = lp;
    __syncthreads();

    unsigned exc_c = 0, exc_p = 0, G = 0;
    for (int i = 0; i < NBINS; ++i) {             // tiny kernel; naive scan fine
        if (i < tid) { exc_c += sc[i]; exc_p += sp[i]; }
        G += sp[i];
    }

    float contrib = 0.0f;
    if (G > 0 && lc > 0) {
        const float fG = (float)G;
        // J(i,m) = 1 - (G-m)/(G+i-m); exact in f32 (counts < 2^23)
        const float Jprev = 1.0f - (fG - (float)exc_p) / (fG + (float)(exc_c - exc_p));
        const unsigned ic = exc_c + lc, mp = exc_p + lp;
        const float Jcur  = 1.0f - (fG - (float)mp) / (fG + (float)(ic - mp));
        const float mid   = ((float)bin + 0.5f) * (1.0f / (float)NBINS);
        contrib = mid * (Jcur - Jprev);
    }

    __shared__ float sf[NBINS];
    sf[tid] = contrib;
    __syncthreads();
    for (int s = NBINS / 2; s > 0; s >>= 1) {
        if (tid < s) sf[tid] += sf[tid + s];
        __syncthreads();
    }
    if (tid == 0) {
        out_pc[cls * 2]     = sf[0];
        out_pc[cls * 2 + 1] = (G > 0) ? 1.0f : 0.0f;
    }
}

__global__ void lovasz_final(const float* __restrict__ out_pc, float* __restrict__ out) {
    if (threadIdx.x == 0 && blockIdx.x == 0) {
        float s = 0.0f, n = 0.0f;
        for (int c = 0; c < NCLS; ++c) {
            s += out_pc[c * 2];
            n += out_pc[c * 2 + 1];
        }
        out[0] = s / n;
    }
}

extern "C" void kernel_launch(void* const* d_in, const int* in_sizes, int n_in,
                              void* d_out, int out_size, void* d_ws, size_t ws_size,
                              hipStream_t stream) {
    const float* pred  = (const float*)d_in[0];
    const int*   label = (const int*)d_in[1];

    unsigned long long* g_hist = (unsigned long long*)d_ws;
    float* out_pc = (float*)(g_hist + (size_t)NCOPY * NCLS * NBINS);
    float* out    = (float*)d_out;

    const int nzero = NCOPY * NCLS * NBINS * 2;  // u64 hist as u32 words
    zero_ws<<<(nzero + 255) / 256, 256, 0, stream>>>((unsigned*)g_hist, nzero);
    lovasz_hist<<<NCHUNK, 256, 0, stream>>>(pred, label, g_hist);
    lovasz_scan<<<NCLS, NBINS, 0, stream>>>(g_hist, out_pc);
    lovasz_final<<<1, 64, 0, stream>>>(out_pc, out);
}